// Round 1
// baseline (226.419 us; speedup 1.0000x reference)
//
#include <hip/hip_runtime.h>

// DfOp: deep-filtering over first N_DF=96 freq bins of spec (B=8,T=3000,F=481,2),
// 5-tap complex FIR along time with per-(b,t,f) coefficients; bins >=96 pass through.
// Memory-bound: ~277 MB compulsory traffic, ~92 MFLOP.

#define BN   8
#define TN   3000
#define FN   481
#define NDF  96
#define NORD 5

__global__ __launch_bounds__(256) void df_kernel(const float* __restrict__ spec,
                                                 const float* __restrict__ coef,
                                                 float* __restrict__ out) {
    const int i = blockIdx.x * blockDim.x + threadIdx.x;
    const int nFilt = BN * TN * NDF;       // 2,304,000
    const int nTot  = BN * TN * FN;        // 11,544,000
    if (i >= nTot) return;

    const int rowStride = FN * 2;          // floats per (b,t) row = 962

    if (i < nFilt) {
        // ---- filtered band ----
        const int f  = i % NDF;
        const int bt = i / NDF;            // b*T + t
        const int t  = bt % TN;

        // coef layout: (B,T,NDF, 2*NORD) -> flat index i*10
        const float2* c2 = (const float2*)(coef + (size_t)i * (2 * NORD));
        const float2 ca = c2[0], cb = c2[1], cc = c2[2], cd = c2[3], ce = c2[4];
        const float cr[NORD] = {ca.x, ca.y, cb.x, cb.y, cc.x};
        const float ci[NORD] = {cc.y, cd.x, cd.y, ce.x, ce.y};

        const int base0 = bt * rowStride + f * 2;   // index of (b,t,f,0)

        float fr = 0.f, fi = 0.f;
        if (t >= NORD - 1) {
            // no padding needed: all 5 taps in-range (vast majority of threads)
            #pragma unroll
            for (int k = 0; k < NORD; ++k) {
                const float2 x = *(const float2*)(spec + base0 + (k - (NORD - 1)) * rowStride);
                fr += x.x * cr[k] - x.y * ci[k];
                fi += x.x * ci[k] + x.y * cr[k];
            }
        } else {
            #pragma unroll
            for (int k = 0; k < NORD; ++k) {
                const int tt = t - (NORD - 1) + k;
                if (tt >= 0) {
                    const float2 x = *(const float2*)(spec + base0 + (k - (NORD - 1)) * rowStride);
                    fr += x.x * cr[k] - x.y * ci[k];
                    fi += x.x * ci[k] + x.y * cr[k];
                }
            }
        }
        *(float2*)(out + base0) = make_float2(fr, fi);
    } else {
        // ---- passthrough band (f in [96, 481)) ----
        const int j  = i - nFilt;
        const int f  = NDF + j % (FN - NDF);
        const int bt = j / (FN - NDF);
        const int idx = bt * rowStride + f * 2;
        *(float2*)(out + idx) = *(const float2*)(spec + idx);
    }
}

extern "C" void kernel_launch(void* const* d_in, const int* in_sizes, int n_in,
                              void* d_out, int out_size, void* d_ws, size_t ws_size,
                              hipStream_t stream) {
    const float* spec = (const float*)d_in[0];
    const float* coef = (const float*)d_in[1];
    float* out = (float*)d_out;

    const int nTot = BN * TN * FN;
    const int block = 256;
    const int grid = (nTot + block - 1) / block;
    df_kernel<<<grid, block, 0, stream>>>(spec, coef, out);
}